// Round 10
// baseline (210.266 us; speedup 1.0000x reference)
//
#include <hip/hip_runtime.h>
#include <hip/hip_bf16.h>
#include <math.h>

#define BB 16
#define TT 2048
#define VV 512

typedef __attribute__((ext_vector_type(8))) short short8;
typedef __attribute__((ext_vector_type(4))) float floatx4;

static __device__ inline ushort f2bf(float f) {
  __hip_bfloat16 h = __float2bfloat16(f);
  return *(ushort*)&h;
}

// async 16B global->LDS DMA. LDS dest = wave-uniform base + lane*16;
// global source is per-lane.
static __device__ __forceinline__ void cp16(const void* g, void* l) {
  __builtin_amdgcn_global_load_lds((const __attribute__((address_space(1))) void*)g,
                                   (__attribute__((address_space(3))) void*)l, 16, 0, 0);
}

// Banded balanced XCD-pinned decode for the GEMM grids (1024 blocks).
// xcd = h&7 (verified: FETCH 233->37 MB, R7). rank = h>>3; CU cc = rank%32
// receives one job per band: t = {15-g, 11-g, 4+g, g}, g = cc>>3 -> per-CU
// K-steps sum to exactly 136. slot = cc&7 encodes (b_hi, col-tile);
// b = xcd | b_hi<<3 keeps batch-b operands in one XCD's L2.
static __device__ __forceinline__ void band_map(int h, int* b, int* ct, int* tt) {
  const int xcd = h & 7, rank = h >> 3;
  const int band = rank >> 5, cc = rank & 31, g = cc >> 3, slot = cc & 7;
  *b = xcd | ((slot >> 2) << 3);
  *ct = slot & 3;
  *tt = (band == 0) ? (15 - g) : (band == 1) ? (11 - g) : (band == 2) ? (4 + g) : g;
}

// ---------------- builders ----------------

// Fused: blocks [0,512) transpose Wq -> WqT; blocks [512,2560) build PE.
__global__ __launch_bounds__(256) void k_pre(const float* __restrict__ Wq,
                                             const float* __restrict__ h,
                                             ushort* __restrict__ WqT,
                                             ushort* __restrict__ PE) {
  const int blk = blockIdx.x;
  if (blk < VV) {
    const int u = blk;
    for (int v = threadIdx.x; v < VV; v += blockDim.x)
      WqT[u * VV + v] = f2bf(Wq[(size_t)v * VV + u]);
  } else {
    const int t = blk - VV;
    ushort* out = PE + (size_t)t * TT;
    for (int p = threadIdx.x; p < TT; p += blockDim.x)
      out[p] = (p <= t) ? f2bf(h[t - p]) : (ushort)0;
  }
}

// M[b,u,p] = WqT[u, idx[b,p]] ; VvT[b,j,s] = Wv[j, idx[b,s]]
// XCD-pinned by b; 8 tokens/thread, 16-B stores (one pass covers T=2048).
__global__ __launch_bounds__(256) void k_build_mv(const int* __restrict__ idx,
                                                  const float* __restrict__ Wv,
                                                  const ushort* __restrict__ WqT,
                                                  ushort* __restrict__ M,
                                                  ushort* __restrict__ VvT) {
  const int h = blockIdx.x;
  const int b = (h & 7) | (((h >> 3) & 1) << 3);
  const int v = h >> 4;
  const int bv = (b << 9) + v;
  __shared__ ushort wrow[VV];
  __shared__ ushort qrow[VV];
  for (int u = threadIdx.x; u < VV; u += blockDim.x) {
    wrow[u] = f2bf(Wv[(size_t)v * VV + u]);
    qrow[u] = WqT[(size_t)v * VV + u];
  }
  __syncthreads();
  const int* row = idx + b * TT;
  ushort* om = M + (size_t)bv * TT;
  ushort* ov = VvT + (size_t)bv * TT;
  const int s8 = threadIdx.x * 8;  // 256 thr * 8 = 2048 = TT exactly
  int4 iv0 = *(const int4*)(row + s8);
  int4 iv1 = *(const int4*)(row + s8 + 4);
  short8 m8, w8;
  m8[0] = qrow[iv0.x];  w8[0] = wrow[iv0.x];
  m8[1] = qrow[iv0.y];  w8[1] = wrow[iv0.y];
  m8[2] = qrow[iv0.z];  w8[2] = wrow[iv0.z];
  m8[3] = qrow[iv0.w];  w8[3] = wrow[iv0.w];
  m8[4] = qrow[iv1.x];  w8[4] = wrow[iv1.x];
  m8[5] = qrow[iv1.y];  w8[5] = wrow[iv1.y];
  m8[6] = qrow[iv1.z];  w8[6] = wrow[iv1.z];
  m8[7] = qrow[iv1.w];  w8[7] = wrow[iv1.w];
  *(short8*)(om + s8) = m8;
  *(short8*)(ov + s8) = w8;
}

// ---------------- 128x128 MFMA GEMM core (R2/R9-verified 2-slot dbuf) -----
// 32 KB LDS -> 4 blocks/CU co-resident with the 1024-block banded grid.

#define GEMM_PRELUDE()                                                         \
  __shared__ __attribute__((aligned(16))) short As[2 * 128 * 32];              \
  __shared__ __attribute__((aligned(16))) short Bs[2 * 128 * 32];              \
  const int tid = threadIdx.x;                                                 \
  const int lane = tid & 63;                                                   \
  const int wm = (tid >> 6) & 1, wn = tid >> 7;                                \
  const int quad = lane >> 4, ln = lane & 15;                                  \
  const int rr = tid >> 2;                                                     \
  const int cg = (((tid & 3) ^ (rr & 3)) << 3);                                \
  short* a_dst = &As[tid * 8];                                                 \
  short* b_dst = &Bs[tid * 8];                                                 \
  const short* ap[4];                                                          \
  const short* bp[4];                                                          \
  _Pragma("unroll") for (int i = 0; i < 4; i++)                                \
      ap[i] = &As[(wm * 64 + i * 16 + ln) * 32 + ((quad ^ (ln & 3)) << 3)];    \
  _Pragma("unroll") for (int j = 0; j < 4; j++)                                \
      bp[j] = &Bs[(wn * 64 + j * 16 + ln) * 32 + ((quad ^ (ln & 3)) << 3)];

#define GEMM_STAGE(c, PA0, PA1, PB0, PB1)                                      \
  {                                                                            \
    const int _o = (c) << 12; /* 4096 shorts = one buffer */                   \
    cp16((PA0), a_dst + _o);                                                   \
    cp16((PA1), a_dst + _o + 2048);                                            \
    cp16((PB0), b_dst + _o);                                                   \
    cp16((PB1), b_dst + _o + 2048);                                            \
  }

// Plain compute. NOTE on data layout: the XOR-swizzle permutes LDS
// *addresses*; the data chunk a lane reads is global k-chunk = quad.
#define GEMM_COMPUTE(c)                                                        \
  {                                                                            \
    const int _o = (c) << 12;                                                  \
    short8 af[4], bfr[4];                                                      \
    _Pragma("unroll") for (int i = 0; i < 4; i++)                              \
        af[i] = *(const short8*)(ap[i] + _o);                                  \
    _Pragma("unroll") for (int j = 0; j < 4; j++)                              \
        bfr[j] = *(const short8*)(bp[j] + _o);                                 \
    _Pragma("unroll") for (int i = 0; i < 4; i++)                              \
        _Pragma("unroll") for (int j = 0; j < 4; j++)                          \
            acc[i][j] = __builtin_amdgcn_mfma_f32_16x16x32_bf16(               \
                af[i], bfr[j], acc[i][j], 0, 0, 0);                            \
  }

// Causal-masked compute for diagonal k-steps: A element at LDS row
// r = wm*64+i*16+ln, global k-col = quad*8+e is kept iff dk+quad*8+e <= r
// (dk = 32*(kt-nk_main); t0 == nk_main*32 cancels). Zeroed otherwise.
#define GEMM_COMPUTE_MASKED(c, DK)                                             \
  {                                                                            \
    const int _o = (c) << 12;                                                  \
    short8 af[4], bfr[4];                                                      \
    _Pragma("unroll") for (int i = 0; i < 4; i++)                              \
        af[i] = *(const short8*)(ap[i] + _o);                                  \
    _Pragma("unroll") for (int j = 0; j < 4; j++)                              \
        bfr[j] = *(const short8*)(bp[j] + _o);                                 \
    _Pragma("unroll") for (int i = 0; i < 4; i++) {                            \
      const int lim = (wm * 64 + i * 16 + ln) - (DK) - (quad << 3);            \
      _Pragma("unroll") for (int e = 0; e < 8; e++)                            \
          if (e > lim) af[i][e] = 0;                                           \
    }                                                                          \
    _Pragma("unroll") for (int i = 0; i < 4; i++)                              \
        _Pragma("unroll") for (int j = 0; j < 4; j++)                          \
            acc[i][j] = __builtin_amdgcn_mfma_f32_16x16x32_bf16(               \
                af[i], bfr[j], acc[i][j], 0, 0, 0);                            \
  }

#define ZERO_ACC()                                                             \
  _Pragma("unroll") for (int i = 0; i < 4; i++)                                \
      _Pragma("unroll") for (int j = 0; j < 4; j++)                            \
          acc[i][j] = (floatx4){0.f, 0.f, 0.f, 0.f};

// GT[b,u,s] = sum_p M[b,u,p] * PE[s,p]  (PE pre-masked -> no diag handling)
__global__ __launch_bounds__(256) void k_gemm_gt(const ushort* __restrict__ M,
                                                 const ushort* __restrict__ PE,
                                                 ushort* __restrict__ GT) {
  int b, u_t, s_t;
  band_map(blockIdx.x, &b, &u_t, &s_t);
  const int u0 = u_t << 7, s0 = s_t << 7;
  const int nk = (s_t << 2) + 4;
  GEMM_PRELUDE();
  const ushort* a_src0 = M + ((size_t)((b << 9) + u0 + rr)) * TT + cg;
  const ushort* a_src1 = a_src0 + (size_t)64 * TT;
  const ushort* b_src0 = PE + (size_t)(s0 + rr) * TT + cg;
  const ushort* b_src1 = b_src0 + (size_t)64 * TT;
  floatx4 acc[4][4];
  ZERO_ACC();
  GEMM_STAGE(0, a_src0, a_src1, b_src0, b_src1);
  __syncthreads();
  int cur = 0;
#pragma unroll 1
  for (int kt = 0; kt < nk; ++kt) {
    if (kt + 1 < nk) {
      const int ko = (kt + 1) << 5;
      GEMM_STAGE(cur ^ 1, a_src0 + ko, a_src1 + ko, b_src0 + ko, b_src1 + ko);
    }
    GEMM_COMPUTE(cur);
    __syncthreads();
    cur ^= 1;
  }
#pragma unroll
  for (int i = 0; i < 4; i++)
#pragma unroll
    for (int j = 0; j < 4; j++) {
      const int rowb = u0 + wm * 64 + i * 16 + quad * 4;
      const int col = s0 + wn * 64 + j * 16 + ln;
#pragma unroll
      for (int r = 0; r < 4; r++)
        GT[((size_t)((b << 9) + rowb + r)) * TT + col] = f2bf(acc[i][j][r]);
    }
}

// logits[b,t,j] = sum_{s<=t} GT[b, idx[b,t], s] * VvT[b,j,s]
// Uniform gather staging over the FULL K range [0, 32*nk); the last 4
// k-steps (s in [t0, t0+128)) apply the causal mask in-register.
__global__ __launch_bounds__(256) void k_gemm2(const int* __restrict__ idx,
                                               const ushort* __restrict__ GT,
                                               const ushort* __restrict__ VvT,
                                               float* __restrict__ out) {
  int b, j_t, t_t;
  band_map(blockIdx.x, &b, &j_t, &t_t);
  const int t0 = t_t << 7, j0 = j_t << 7;
  const int nk_main = t_t << 2;
  const int nk = nk_main + 4;
  GEMM_PRELUDE();
  const int u0 = idx[(b << 11) + t0 + rr];
  const int u1 = idx[(b << 11) + t0 + rr + 64];
  const ushort* a_src0 = GT + ((size_t)(b << 9) + u0) * TT + cg;
  const ushort* a_src1 = GT + ((size_t)(b << 9) + u1) * TT + cg;
  const ushort* b_src0 = VvT + ((size_t)((b << 9) + j0 + rr)) * TT + cg;
  const ushort* b_src1 = b_src0 + (size_t)64 * TT;
  floatx4 acc[4][4];
  ZERO_ACC();
  GEMM_STAGE(0, a_src0, a_src1, b_src0, b_src1);
  __syncthreads();
  int cur = 0;
#pragma unroll 1
  for (int kt = 0; kt < nk; ++kt) {
    if (kt + 1 < nk) {
      const int ko = (kt + 1) << 5;
      GEMM_STAGE(cur ^ 1, a_src0 + ko, a_src1 + ko, b_src0 + ko, b_src1 + ko);
    }
    if (kt < nk_main) {
      GEMM_COMPUTE(cur);
    } else {
      const int dk = (kt - nk_main) << 5;
      GEMM_COMPUTE_MASKED(cur, dk);
    }
    __syncthreads();
    cur ^= 1;
  }
#pragma unroll
  for (int i = 0; i < 4; i++)
#pragma unroll
    for (int j = 0; j < 4; j++) {
      const int rowb = t0 + wm * 64 + i * 16 + quad * 4;
      const int col = j0 + wn * 64 + j * 16 + ln;
#pragma unroll
      for (int r = 0; r < 4; r++)
        out[((size_t)((b << 11) + rowb + r)) * VV + col] = acc[i][j][r];
    }
}

extern "C" void kernel_launch(void* const* d_in, const int* in_sizes, int n_in,
                              void* d_out, int out_size, void* d_ws, size_t ws_size,
                              hipStream_t stream) {
  const int* idx = (const int*)d_in[0];
  const float* pos_table = (const float*)d_in[1];
  const float* Wq = (const float*)d_in[2];
  const float* Wv = (const float*)d_in[3];
  float* out = (float*)d_out;

  char* ws = (char*)d_ws;
  // ws layout (bytes):
  //   WqT bf16 (V,V)        :         0 ..    524288
  //   PE  bf16 (T,T)        :    524288 ..   8912896
  //   M   bf16 (B,V,T)      :   8912896 ..  42467328
  //   VvT bf16 (B,V,T)      :  42467328 ..  76021760
  //   GT  bf16 (B,V,T)      :  76021760 .. 109576192
  ushort* WqT = (ushort*)(ws);
  ushort* PE = (ushort*)(ws + 524288UL);
  ushort* M = (ushort*)(ws + 8912896UL);
  ushort* VvT = (ushort*)(ws + 42467328UL);
  ushort* GT = (ushort*)(ws + 76021760UL);

  k_pre<<<dim3(VV + TT), 256, 0, stream>>>(Wq, pos_table, WqT, PE);
  k_build_mv<<<dim3(BB * VV), 256, 0, stream>>>(idx, Wv, WqT, M, VvT);
  k_gemm_gt<<<dim3(1024), 256, 0, stream>>>(M, PE, GT);
  k_gemm2<<<dim3(1024), 256, 0, stream>>>(idx, GT, VvT, out);
}

// Round 11
// 193.558 us; speedup vs baseline: 1.0863x; 1.0863x over previous
//
#include <hip/hip_runtime.h>
#include <hip/hip_bf16.h>
#include <math.h>

#define BB 16
#define TT 2048
#define VV 512

typedef __attribute__((ext_vector_type(8))) short short8;
typedef __attribute__((ext_vector_type(4))) float floatx4;

static __device__ inline ushort f2bf(float f) {
  __hip_bfloat16 h = __float2bfloat16(f);
  return *(ushort*)&h;
}

// async 16B global->LDS DMA. LDS dest = wave-uniform base + lane*16;
// global source is per-lane.
static __device__ __forceinline__ void cp16(const void* g, void* l) {
  __builtin_amdgcn_global_load_lds((const __attribute__((address_space(1))) void*)g,
                                   (__attribute__((address_space(3))) void*)l, 16, 0, 0);
}

// Banded balanced XCD-pinned decode for the GEMM grids (1024 blocks).
// xcd = h&7 (verified: FETCH 233->37 MB, R7). rank = h>>3; CU cc = rank%32
// receives one job per band: t = {15-g, 11-g, 4+g, g}, g = cc>>3 -> per-CU
// K-steps sum to exactly 136. slot = cc&7 encodes (b_hi, col-tile);
// b = xcd | b_hi<<3 keeps batch-b operands in one XCD's L2.
static __device__ __forceinline__ void band_map(int h, int* b, int* ct, int* tt) {
  const int xcd = h & 7, rank = h >> 3;
  const int band = rank >> 5, cc = rank & 31, g = cc >> 3, slot = cc & 7;
  *b = xcd | ((slot >> 2) << 3);
  *ct = slot & 3;
  *tt = (band == 0) ? (15 - g) : (band == 1) ? (11 - g) : (band == 2) ? (4 + g) : g;
}

// ---------------- builders ----------------

// Fused: blocks [0,512) transpose Wq -> WqT; blocks [512,2560) build PE.
__global__ __launch_bounds__(256) void k_pre(const float* __restrict__ Wq,
                                             const float* __restrict__ h,
                                             ushort* __restrict__ WqT,
                                             ushort* __restrict__ PE) {
  const int blk = blockIdx.x;
  if (blk < VV) {
    const int u = blk;
    for (int v = threadIdx.x; v < VV; v += blockDim.x)
      WqT[u * VV + v] = f2bf(Wq[(size_t)v * VV + u]);
  } else {
    const int t = blk - VV;
    ushort* out = PE + (size_t)t * TT;
    for (int p = threadIdx.x; p < TT; p += blockDim.x)
      out[p] = (p <= t) ? f2bf(h[t - p]) : (ushort)0;
  }
}

// M[b,u,p] = WqT[u, idx[b,p]] ; VvT[b,j,s] = Wv[j, idx[b,s]]
// XCD-pinned by b; 8 tokens/thread, 16-B stores. qrow/wrow packed into one
// uint LDS array -> one ds_read_b32 per token (vs two ds_read_u16).
__global__ __launch_bounds__(256) void k_build_mv(const int* __restrict__ idx,
                                                  const float* __restrict__ Wv,
                                                  const ushort* __restrict__ WqT,
                                                  ushort* __restrict__ M,
                                                  ushort* __restrict__ VvT) {
  const int h = blockIdx.x;
  const int b = (h & 7) | (((h >> 3) & 1) << 3);
  const int v = h >> 4;
  const int bv = (b << 9) + v;
  __shared__ unsigned int comb[VV];  // lo16 = WqT[v,u], hi16 = bf16(Wv[v,u])
  for (int u = threadIdx.x; u < VV; u += blockDim.x) {
    const unsigned int q = WqT[(size_t)v * VV + u];
    const unsigned int w = f2bf(Wv[(size_t)v * VV + u]);
    comb[u] = q | (w << 16);
  }
  __syncthreads();
  const int* row = idx + b * TT;
  ushort* om = M + (size_t)bv * TT;
  ushort* ov = VvT + (size_t)bv * TT;
  const int s8 = threadIdx.x * 8;  // 256 thr * 8 = 2048 = TT exactly
  int4 iv0 = *(const int4*)(row + s8);
  int4 iv1 = *(const int4*)(row + s8 + 4);
  unsigned int c0 = comb[iv0.x], c1 = comb[iv0.y], c2 = comb[iv0.z],
               c3 = comb[iv0.w];
  unsigned int c4 = comb[iv1.x], c5 = comb[iv1.y], c6 = comb[iv1.z],
               c7 = comb[iv1.w];
  short8 m8, w8;
  m8[0] = (short)(c0 & 0xFFFF);  w8[0] = (short)(c0 >> 16);
  m8[1] = (short)(c1 & 0xFFFF);  w8[1] = (short)(c1 >> 16);
  m8[2] = (short)(c2 & 0xFFFF);  w8[2] = (short)(c2 >> 16);
  m8[3] = (short)(c3 & 0xFFFF);  w8[3] = (short)(c3 >> 16);
  m8[4] = (short)(c4 & 0xFFFF);  w8[4] = (short)(c4 >> 16);
  m8[5] = (short)(c5 & 0xFFFF);  w8[5] = (short)(c5 >> 16);
  m8[6] = (short)(c6 & 0xFFFF);  w8[6] = (short)(c6 >> 16);
  m8[7] = (short)(c7 & 0xFFFF);  w8[7] = (short)(c7 >> 16);
  *(short8*)(om + s8) = m8;
  *(short8*)(ov + s8) = w8;
}

// ---------------- 128x128 MFMA GEMM core (R2/R9-verified 2-slot dbuf) -----
// 32 KB LDS -> 4 blocks/CU co-resident with the 1024-block banded grid.

#define GEMM_PRELUDE()                                                         \
  __shared__ __attribute__((aligned(16))) short As[2 * 128 * 32];              \
  __shared__ __attribute__((aligned(16))) short Bs[2 * 128 * 32];              \
  const int tid = threadIdx.x;                                                 \
  const int lane = tid & 63;                                                   \
  const int wm = (tid >> 6) & 1, wn = tid >> 7;                                \
  const int quad = lane >> 4, ln = lane & 15;                                  \
  const int rr = tid >> 2;                                                     \
  const int cg = (((tid & 3) ^ (rr & 3)) << 3);                                \
  short* a_dst = &As[tid * 8];                                                 \
  short* b_dst = &Bs[tid * 8];                                                 \
  const short* ap[4];                                                          \
  const short* bp[4];                                                          \
  _Pragma("unroll") for (int i = 0; i < 4; i++)                                \
      ap[i] = &As[(wm * 64 + i * 16 + ln) * 32 + ((quad ^ (ln & 3)) << 3)];    \
  _Pragma("unroll") for (int j = 0; j < 4; j++)                                \
      bp[j] = &Bs[(wn * 64 + j * 16 + ln) * 32 + ((quad ^ (ln & 3)) << 3)];

#define GEMM_STAGE(c, PA0, PA1, PB0, PB1)                                      \
  {                                                                            \
    const int _o = (c) << 12; /* 4096 shorts = one buffer */                   \
    cp16((PA0), a_dst + _o);                                                   \
    cp16((PA1), a_dst + _o + 2048);                                            \
    cp16((PB0), b_dst + _o);                                                   \
    cp16((PB1), b_dst + _o + 2048);                                            \
  }

#define GEMM_COMPUTE(c)                                                        \
  {                                                                            \
    const int _o = (c) << 12;                                                  \
    short8 af[4], bfr[4];                                                      \
    _Pragma("unroll") for (int i = 0; i < 4; i++)                              \
        af[i] = *(const short8*)(ap[i] + _o);                                  \
    _Pragma("unroll") for (int j = 0; j < 4; j++)                              \
        bfr[j] = *(const short8*)(bp[j] + _o);                                 \
    _Pragma("unroll") for (int i = 0; i < 4; i++)                              \
        _Pragma("unroll") for (int j = 0; j < 4; j++)                          \
            acc[i][j] = __builtin_amdgcn_mfma_f32_16x16x32_bf16(               \
                af[i], bfr[j], acc[i][j], 0, 0, 0);                            \
  }

#define ZERO_ACC()                                                             \
  _Pragma("unroll") for (int i = 0; i < 4; i++)                                \
      _Pragma("unroll") for (int j = 0; j < 4; j++)                            \
          acc[i][j] = (floatx4){0.f, 0.f, 0.f, 0.f};

// 2-slot double-buffered loop (R2-verified): stage k+1, compute k, barrier.
#define DBUF_LOOP(NK, STAGE_AT)                                                \
  {                                                                            \
    STAGE_AT(0, 0);                                                            \
    __syncthreads();                                                           \
    int cur = 0;                                                               \
    _Pragma("unroll 1") for (int kt = 0; kt < (NK); ++kt) {                    \
      if (kt + 1 < (NK)) STAGE_AT(cur ^ 1, kt + 1);                            \
      GEMM_COMPUTE(cur);                                                       \
      __syncthreads();                                                         \
      cur ^= 1;                                                                \
    }                                                                          \
  }

// GT[b,u,s] = sum_p M[b,u,p] * PE[s,p]  (causal K-extent: p < 128*(s_t+1))
__global__ __launch_bounds__(256) void k_gemm_gt(const ushort* __restrict__ M,
                                                 const ushort* __restrict__ PE,
                                                 ushort* __restrict__ GT) {
  int b, u_t, s_t;
  band_map(blockIdx.x, &b, &u_t, &s_t);
  const int u0 = u_t << 7, s0 = s_t << 7;
  const int nk = (s_t << 2) + 4;
  GEMM_PRELUDE();
  const ushort* a_src0 = M + ((size_t)((b << 9) + u0 + rr)) * TT + cg;
  const ushort* a_src1 = a_src0 + (size_t)64 * TT;
  const ushort* b_src0 = PE + (size_t)(s0 + rr) * TT + cg;
  const ushort* b_src1 = b_src0 + (size_t)64 * TT;
  floatx4 acc[4][4];
  ZERO_ACC();
#define SA_GT(c, k)                                                            \
  GEMM_STAGE(c, a_src0 + ((k) << 5), a_src1 + ((k) << 5), b_src0 + ((k) << 5), \
             b_src1 + ((k) << 5))
  DBUF_LOOP(nk, SA_GT);
#undef SA_GT
#pragma unroll
  for (int i = 0; i < 4; i++)
#pragma unroll
    for (int j = 0; j < 4; j++) {
      const int rowb = u0 + wm * 64 + i * 16 + quad * 4;
      const int col = s0 + wn * 64 + j * 16 + ln;
#pragma unroll
      for (int r = 0; r < 4; r++)
        GT[((size_t)((b << 9) + rowb + r)) * TT + col] = f2bf(acc[i][j][r]);
    }
}

// Pre-masked diagonal tiles: a2d[b][t_t][r][c] = (c<=r) ? GT[b, idx[b,t0+r], t0+c] : 0
// XCD-pinned by b (reads GT[b] warm, writes a2d[b] into consumer's L2).
__global__ __launch_bounds__(256) void k_diag(const int* __restrict__ idx,
                                              const ushort* __restrict__ GT,
                                              ushort* __restrict__ a2d) {
  const int h = blockIdx.x;
  const int b = (h & 7) | (((h >> 3) & 1) << 3);
  const int t_t = (h >> 4) & 15;
  const int t0 = t_t << 7;
  ushort* outt = a2d + (((size_t)(b << 4) + t_t) << 14);
  for (int e = threadIdx.x; e < 2048; e += 256) {
    const int r = e >> 4;
    const int c8 = (e & 15) << 3;
    const int u = idx[(b << 11) + t0 + r];
    const ushort* src = GT + ((size_t)((b << 9) + u)) * TT + t0 + c8;
    ushort4 lo = *(const ushort4*)(src);
    ushort4 hi = *(const ushort4*)(src + 4);
    ushort vals[8] = {lo.x, lo.y, lo.z, lo.w, hi.x, hi.y, hi.z, hi.w};
    ushort o[8];
#pragma unroll
    for (int k = 0; k < 8; ++k) o[k] = (c8 + k <= r) ? vals[k] : (ushort)0;
    *(ushort4*)(outt + r * 128 + c8) = *(ushort4*)&o[0];
    *(ushort4*)(outt + r * 128 + c8 + 4) = *(ushort4*)&o[4];
  }
}

// logits[b,t,j] = sum_{s<=t} GT[b, idx[b,t], s] * VvT[b,j,s]
// Banded grid: ct = j-tile, tt = t-tile. K-loop unified: kt < nk_main ->
// gathered GT rows (below diagonal); kt >= nk_main -> pre-masked diag tile.
__global__ __launch_bounds__(256) void k_gemm2(const int* __restrict__ idx,
                                               const ushort* __restrict__ GT,
                                               const ushort* __restrict__ a2d,
                                               const ushort* __restrict__ VvT,
                                               float* __restrict__ out) {
  int b, j_t, t_t;
  band_map(blockIdx.x, &b, &j_t, &t_t);
  const int t0 = t_t << 7, j0 = j_t << 7;
  const int nk_main = t_t << 2;
  const int nk = nk_main + 4;
  GEMM_PRELUDE();
  const int u0 = idx[(b << 11) + t0 + rr];
  const int u1 = idx[(b << 11) + t0 + rr + 64];
  const ushort* a_src0 = GT + ((size_t)(b << 9) + u0) * TT + cg;
  const ushort* a_src1 = GT + ((size_t)(b << 9) + u1) * TT + cg;
  const ushort* b_src0 = VvT + ((size_t)((b << 9) + j0 + rr)) * TT + cg;
  const ushort* b_src1 = b_src0 + (size_t)64 * TT;
  const ushort* ad0 = a2d + (((size_t)(b << 4) + t_t) << 14) + (size_t)rr * 128 + cg;
  const ushort* ad1 = ad0 + (size_t)64 * 128;
  floatx4 acc[4][4];
  ZERO_ACC();
#define SA_G2(c, k)                                                            \
  GEMM_STAGE(c,                                                                \
             (k) < nk_main ? a_src0 + ((k) << 5) : ad0 + (((k) - nk_main) << 5), \
             (k) < nk_main ? a_src1 + ((k) << 5) : ad1 + (((k) - nk_main) << 5), \
             b_src0 + ((k) << 5), b_src1 + ((k) << 5))
  DBUF_LOOP(nk, SA_G2);
#undef SA_G2
#pragma unroll
  for (int i = 0; i < 4; i++)
#pragma unroll
    for (int j = 0; j < 4; j++) {
      const int rowb = t0 + wm * 64 + i * 16 + quad * 4;
      const int col = j0 + wn * 64 + j * 16 + ln;
#pragma unroll
      for (int r = 0; r < 4; r++)
        out[((size_t)((b << 11) + rowb + r)) * VV + col] = acc[i][j][r];
    }
}

extern "C" void kernel_launch(void* const* d_in, const int* in_sizes, int n_in,
                              void* d_out, int out_size, void* d_ws, size_t ws_size,
                              hipStream_t stream) {
  const int* idx = (const int*)d_in[0];
  const float* pos_table = (const float*)d_in[1];
  const float* Wq = (const float*)d_in[2];
  const float* Wv = (const float*)d_in[3];
  float* out = (float*)d_out;

  char* ws = (char*)d_ws;
  // ws layout (bytes):
  //   WqT bf16 (V,V)        :         0 ..    524288
  //   PE  bf16 (T,T)        :    524288 ..   8912896
  //   M   bf16 (B,V,T)      :   8912896 ..  42467328
  //   VvT bf16 (B,V,T)      :  42467328 ..  76021760
  //   GT  bf16 (B,V,T)      :  76021760 .. 109576192
  //   a2d bf16 (B,16,128^2) : 109576192 .. 117964800
  ushort* WqT = (ushort*)(ws);
  ushort* PE = (ushort*)(ws + 524288UL);
  ushort* M = (ushort*)(ws + 8912896UL);
  ushort* VvT = (ushort*)(ws + 42467328UL);
  ushort* GT = (ushort*)(ws + 76021760UL);
  ushort* a2d = (ushort*)(ws + 109576192UL);

  k_pre<<<dim3(VV + TT), 256, 0, stream>>>(Wq, pos_table, WqT, PE);
  k_build_mv<<<dim3(BB * VV), 256, 0, stream>>>(idx, Wv, WqT, M, VvT);
  k_gemm_gt<<<dim3(1024), 256, 0, stream>>>(M, PE, GT);
  k_diag<<<dim3(256), 256, 0, stream>>>(idx, GT, a2d);
  k_gemm2<<<dim3(1024), 256, 0, stream>>>(idx, GT, a2d, VvT, out);
}

// Round 12
// 186.055 us; speedup vs baseline: 1.1301x; 1.0403x over previous
//
#include <hip/hip_runtime.h>
#include <hip/hip_bf16.h>
#include <math.h>

#define BB 16
#define TT 2048
#define VV 512

typedef __attribute__((ext_vector_type(8))) short short8;
typedef __attribute__((ext_vector_type(4))) float floatx4;

static __device__ inline ushort f2bf(float f) {
  __hip_bfloat16 h = __float2bfloat16(f);
  return *(ushort*)&h;
}

// async 16B global->LDS DMA. LDS dest = wave-uniform base + lane*16;
// global source is per-lane.
static __device__ __forceinline__ void cp16(const void* g, void* l) {
  __builtin_amdgcn_global_load_lds((const __attribute__((address_space(1))) void*)g,
                                   (__attribute__((address_space(3))) void*)l, 16, 0, 0);
}

// Banded balanced XCD-pinned decode for the GEMM grids (1024 blocks).
// xcd = h&7 (verified: FETCH 233->37 MB, R7). rank = h>>3; CU cc = rank%32
// receives one job per band: t = {15-g, 11-g, 4+g, g}, g = cc>>3 -> per-CU
// K-steps sum to exactly 136. slot = cc&7 encodes (b_hi, col-tile);
// b = xcd | b_hi<<3 keeps batch-b operands in one XCD's L2.
static __device__ __forceinline__ void band_map(int h, int* b, int* ct, int* tt) {
  const int xcd = h & 7, rank = h >> 3;
  const int band = rank >> 5, cc = rank & 31, g = cc >> 3, slot = cc & 7;
  *b = xcd | ((slot >> 2) << 3);
  *ct = slot & 3;
  *tt = (band == 0) ? (15 - g) : (band == 1) ? (11 - g) : (band == 2) ? (4 + g) : g;
}

// ---------------- builders ----------------

// Fused: blocks [0,512) transpose Wq -> WqT; blocks [512,2560) build PE.
__global__ __launch_bounds__(256) void k_pre(const float* __restrict__ Wq,
                                             const float* __restrict__ h,
                                             ushort* __restrict__ WqT,
                                             ushort* __restrict__ PE) {
  const int blk = blockIdx.x;
  if (blk < VV) {
    const int u = blk;
    for (int v = threadIdx.x; v < VV; v += blockDim.x)
      WqT[u * VV + v] = f2bf(Wq[(size_t)v * VV + u]);
  } else {
    const int t = blk - VV;
    ushort* out = PE + (size_t)t * TT;
    for (int p = threadIdx.x; p < TT; p += blockDim.x)
      out[p] = (p <= t) ? f2bf(h[t - p]) : (ushort)0;
  }
}

// M[b,u,p] = WqT[u, idx[b,p]] ; VvT[b,j,s] = Wv[j, idx[b,s]]
// XCD-pinned by b; 8 tokens/thread, 16-B stores. qrow/wrow packed into one
// uint LDS array -> one ds_read_b32 per token (vs two ds_read_u16).
__global__ __launch_bounds__(256) void k_build_mv(const int* __restrict__ idx,
                                                  const float* __restrict__ Wv,
                                                  const ushort* __restrict__ WqT,
                                                  ushort* __restrict__ M,
                                                  ushort* __restrict__ VvT) {
  const int h = blockIdx.x;
  const int b = (h & 7) | (((h >> 3) & 1) << 3);
  const int v = h >> 4;
  const int bv = (b << 9) + v;
  __shared__ unsigned int comb[VV];  // lo16 = WqT[v,u], hi16 = bf16(Wv[v,u])
  for (int u = threadIdx.x; u < VV; u += blockDim.x) {
    const unsigned int q = WqT[(size_t)v * VV + u];
    const unsigned int w = f2bf(Wv[(size_t)v * VV + u]);
    comb[u] = q | (w << 16);
  }
  __syncthreads();
  const int* row = idx + b * TT;
  ushort* om = M + (size_t)bv * TT;
  ushort* ov = VvT + (size_t)bv * TT;
  const int s8 = threadIdx.x * 8;  // 256 thr * 8 = 2048 = TT exactly
  int4 iv0 = *(const int4*)(row + s8);
  int4 iv1 = *(const int4*)(row + s8 + 4);
  unsigned int c0 = comb[iv0.x], c1 = comb[iv0.y], c2 = comb[iv0.z],
               c3 = comb[iv0.w];
  unsigned int c4 = comb[iv1.x], c5 = comb[iv1.y], c6 = comb[iv1.z],
               c7 = comb[iv1.w];
  short8 m8, w8;
  m8[0] = (short)(c0 & 0xFFFF);  w8[0] = (short)(c0 >> 16);
  m8[1] = (short)(c1 & 0xFFFF);  w8[1] = (short)(c1 >> 16);
  m8[2] = (short)(c2 & 0xFFFF);  w8[2] = (short)(c2 >> 16);
  m8[3] = (short)(c3 & 0xFFFF);  w8[3] = (short)(c3 >> 16);
  m8[4] = (short)(c4 & 0xFFFF);  w8[4] = (short)(c4 >> 16);
  m8[5] = (short)(c5 & 0xFFFF);  w8[5] = (short)(c5 >> 16);
  m8[6] = (short)(c6 & 0xFFFF);  w8[6] = (short)(c6 >> 16);
  m8[7] = (short)(c7 & 0xFFFF);  w8[7] = (short)(c7 >> 16);
  *(short8*)(om + s8) = m8;
  *(short8*)(ov + s8) = w8;
}

// ---------------- 128x128 MFMA GEMM core (R2/R9-verified 2-slot dbuf) -----
// 32 KB LDS -> 4 blocks/CU co-resident with the 1024-block banded grid.

#define GEMM_PRELUDE()                                                         \
  __shared__ __attribute__((aligned(16))) short As[2 * 128 * 32];              \
  __shared__ __attribute__((aligned(16))) short Bs[2 * 128 * 32];              \
  const int tid = threadIdx.x;                                                 \
  const int lane = tid & 63;                                                   \
  const int wm = (tid >> 6) & 1, wn = tid >> 7;                                \
  const int quad = lane >> 4, ln = lane & 15;                                  \
  const int rr = tid >> 2;                                                     \
  const int cg = (((tid & 3) ^ (rr & 3)) << 3);                                \
  short* a_dst = &As[tid * 8];                                                 \
  short* b_dst = &Bs[tid * 8];                                                 \
  const short* ap[4];                                                          \
  const short* bp[4];                                                          \
  _Pragma("unroll") for (int i = 0; i < 4; i++)                                \
      ap[i] = &As[(wm * 64 + i * 16 + ln) * 32 + ((quad ^ (ln & 3)) << 3)];    \
  _Pragma("unroll") for (int j = 0; j < 4; j++)                                \
      bp[j] = &Bs[(wn * 64 + j * 16 + ln) * 32 + ((quad ^ (ln & 3)) << 3)];

#define GEMM_STAGE(c, PA0, PA1, PB0, PB1)                                      \
  {                                                                            \
    const int _o = (c) << 12; /* 4096 shorts = one buffer */                   \
    cp16((PA0), a_dst + _o);                                                   \
    cp16((PA1), a_dst + _o + 2048);                                            \
    cp16((PB0), b_dst + _o);                                                   \
    cp16((PB1), b_dst + _o + 2048);                                            \
  }

#define GEMM_COMPUTE(c)                                                        \
  {                                                                            \
    const int _o = (c) << 12;                                                  \
    short8 af[4], bfr[4];                                                      \
    _Pragma("unroll") for (int i = 0; i < 4; i++)                              \
        af[i] = *(const short8*)(ap[i] + _o);                                  \
    _Pragma("unroll") for (int j = 0; j < 4; j++)                              \
        bfr[j] = *(const short8*)(bp[j] + _o);                                 \
    _Pragma("unroll") for (int i = 0; i < 4; i++)                              \
        _Pragma("unroll") for (int j = 0; j < 4; j++)                          \
            acc[i][j] = __builtin_amdgcn_mfma_f32_16x16x32_bf16(               \
                af[i], bfr[j], acc[i][j], 0, 0, 0);                            \
  }

#define ZERO_ACC()                                                             \
  _Pragma("unroll") for (int i = 0; i < 4; i++)                                \
      _Pragma("unroll") for (int j = 0; j < 4; j++)                            \
          acc[i][j] = (floatx4){0.f, 0.f, 0.f, 0.f};

// 2-slot double-buffered loop (R2-verified): stage k+1, compute k, barrier.
#define DBUF_LOOP(NK, STAGE_AT)                                                \
  {                                                                            \
    STAGE_AT(0, 0);                                                            \
    __syncthreads();                                                           \
    int cur = 0;                                                               \
    _Pragma("unroll 1") for (int kt = 0; kt < (NK); ++kt) {                    \
      if (kt + 1 < (NK)) STAGE_AT(cur ^ 1, kt + 1);                            \
      GEMM_COMPUTE(cur);                                                       \
      __syncthreads();                                                         \
      cur ^= 1;                                                                \
    }                                                                          \
  }

// GT[b,u,s] = sum_p M[b,u,p] * PE[s,p]  (causal K-extent: p < 128*(s_t+1))
__global__ __launch_bounds__(256) void k_gemm_gt(const ushort* __restrict__ M,
                                                 const ushort* __restrict__ PE,
                                                 ushort* __restrict__ GT) {
  int b, u_t, s_t;
  band_map(blockIdx.x, &b, &u_t, &s_t);
  const int u0 = u_t << 7, s0 = s_t << 7;
  const int nk = (s_t << 2) + 4;
  GEMM_PRELUDE();
  const ushort* a_src0 = M + ((size_t)((b << 9) + u0 + rr)) * TT + cg;
  const ushort* a_src1 = a_src0 + (size_t)64 * TT;
  const ushort* b_src0 = PE + (size_t)(s0 + rr) * TT + cg;
  const ushort* b_src1 = b_src0 + (size_t)64 * TT;
  floatx4 acc[4][4];
  ZERO_ACC();
#define SA_GT(c, k)                                                            \
  GEMM_STAGE(c, a_src0 + ((k) << 5), a_src1 + ((k) << 5), b_src0 + ((k) << 5), \
             b_src1 + ((k) << 5))
  DBUF_LOOP(nk, SA_GT);
#undef SA_GT
#pragma unroll
  for (int i = 0; i < 4; i++)
#pragma unroll
    for (int j = 0; j < 4; j++) {
      const int rowb = u0 + wm * 64 + i * 16 + quad * 4;
      const int col = s0 + wn * 64 + j * 16 + ln;
#pragma unroll
      for (int r = 0; r < 4; r++)
        GT[((size_t)((b << 9) + rowb + r)) * TT + col] = f2bf(acc[i][j][r]);
    }
}

// logits[b,t,j] = sum_{s<=t} GT[b, idx[b,t], s] * VvT[b,j,s]
// Diagonal k-steps (kt >= nk_main) are handled by masked REG-staging of A:
// the gathered pointers already address GT[..., t0+dk+cg+e] (kt*32 = t0+dk),
// and the causal mask reduces to  dk+cg+e <= rr (row rr) / rr+64 (row rr+64).
// Mask lives at stage time (2 transient short8s), NOT in the MFMA cluster
// (R10 lesson: in-cluster masking -> VGPR 104, -26 us).
__global__ __launch_bounds__(256) void k_gemm2(const int* __restrict__ idx,
                                               const ushort* __restrict__ GT,
                                               const ushort* __restrict__ VvT,
                                               float* __restrict__ out) {
  int b, j_t, t_t;
  band_map(blockIdx.x, &b, &j_t, &t_t);
  const int t0 = t_t << 7, j0 = j_t << 7;
  const int nk_main = t_t << 2;
  const int nk = nk_main + 4;
  GEMM_PRELUDE();
  const int u0 = idx[(b << 11) + t0 + rr];
  const int u1 = idx[(b << 11) + t0 + rr + 64];
  const ushort* a_src0 = GT + ((size_t)(b << 9) + u0) * TT + cg;
  const ushort* a_src1 = GT + ((size_t)(b << 9) + u1) * TT + cg;
  const ushort* b_src0 = VvT + ((size_t)((b << 9) + j0 + rr)) * TT + cg;
  const ushort* b_src1 = b_src0 + (size_t)64 * TT;
  floatx4 acc[4][4];
  ZERO_ACC();
#define SA_G2(c, k)                                                            \
  {                                                                            \
    const int _o = (c) << 12;                                                  \
    const int _ko = (k) << 5;                                                  \
    cp16(b_src0 + _ko, b_dst + _o);                                            \
    cp16(b_src1 + _ko, b_dst + _o + 2048);                                     \
    if ((k) < nk_main) {                                                       \
      cp16(a_src0 + _ko, a_dst + _o);                                          \
      cp16(a_src1 + _ko, a_dst + _o + 2048);                                   \
    } else {                                                                   \
      short8 _a0 = *(const short8*)(a_src0 + _ko);                             \
      short8 _a1 = *(const short8*)(a_src1 + _ko);                             \
      const int _lim = rr - (((k) - nk_main) << 5) - cg;                       \
      _Pragma("unroll") for (int _e = 0; _e < 8; _e++) {                       \
        if (_e > _lim) _a0[_e] = 0;                                            \
        if (_e > _lim + 64) _a1[_e] = 0;                                       \
      }                                                                        \
      *(short8*)(a_dst + _o) = _a0;                                            \
      *(short8*)(a_dst + _o + 2048) = _a1;                                     \
    }                                                                          \
  }
  DBUF_LOOP(nk, SA_G2);
#undef SA_G2
#pragma unroll
  for (int i = 0; i < 4; i++)
#pragma unroll
    for (int j = 0; j < 4; j++) {
      const int rowb = t0 + wm * 64 + i * 16 + quad * 4;
      const int col = j0 + wn * 64 + j * 16 + ln;
#pragma unroll
      for (int r = 0; r < 4; r++)
        out[((size_t)((b << 11) + rowb + r)) * VV + col] = acc[i][j][r];
    }
}

extern "C" void kernel_launch(void* const* d_in, const int* in_sizes, int n_in,
                              void* d_out, int out_size, void* d_ws, size_t ws_size,
                              hipStream_t stream) {
  const int* idx = (const int*)d_in[0];
  const float* pos_table = (const float*)d_in[1];
  const float* Wq = (const float*)d_in[2];
  const float* Wv = (const float*)d_in[3];
  float* out = (float*)d_out;

  char* ws = (char*)d_ws;
  // ws layout (bytes):
  //   WqT bf16 (V,V)        :         0 ..    524288
  //   PE  bf16 (T,T)        :    524288 ..   8912896
  //   M   bf16 (B,V,T)      :   8912896 ..  42467328
  //   VvT bf16 (B,V,T)      :  42467328 ..  76021760
  //   GT  bf16 (B,V,T)      :  76021760 .. 109576192
  ushort* WqT = (ushort*)(ws);
  ushort* PE = (ushort*)(ws + 524288UL);
  ushort* M = (ushort*)(ws + 8912896UL);
  ushort* VvT = (ushort*)(ws + 42467328UL);
  ushort* GT = (ushort*)(ws + 76021760UL);

  k_pre<<<dim3(VV + TT), 256, 0, stream>>>(Wq, pos_table, WqT, PE);
  k_build_mv<<<dim3(BB * VV), 256, 0, stream>>>(idx, Wv, WqT, M, VvT);
  k_gemm_gt<<<dim3(1024), 256, 0, stream>>>(M, PE, GT);
  k_gemm2<<<dim3(1024), 256, 0, stream>>>(idx, GT, VvT, out);
}